// Round 2
// baseline (2100.612 us; speedup 1.0000x reference)
//
#include <hip/hip_runtime.h>
#include <hip/hip_bf16.h>

// ContextualEncoder2: 5 GRU cells, N=16384, H=1024, INPUT=1088. fp32 in/out (per reference);
// compute in bf16 MFMA with fp32 accumulate (threshold = 2% of max|ref| = 1.47e-2).
// Algebraic restructure:
//   steps 0-2: gi = obs_t @ Wih[:, :64]^T + E[id]  where E = emb @ Wih[:,64:]^T + b_ih (100 ids, fp32)
//   steps 3-4: gi = [h | obs_t] @ Wih^T + b_ih   (h stored in 1088-wide padded bf16 buffer)
//   gates fused into GEMM epilogue with 4 accum quantities: r_sum, z_sum, gi_n, gh_n.
// R2 change: NO LDS AT ALL. Both MFMA fragments are contiguous 16B/lane in the row-major
// sources, so each fragment is one global_load_dwordx4 straight to VGPR. This removes:
// all barriers (compiler now emits counted vmcnt => true pipelining), all LDS bank
// conflicts (was 2.16e7 cyc/dispatch), the ~65%-busy LDS pipe, and staging VALU.
// Reuse is served by L1 (2x intra-block), L2/L3 (cross-block), same as the staged fetch.
// Register 2-deep pipeline at 32-K granularity with NAMED buffer sets (no runtime idx).

typedef __bf16 bf16_4 __attribute__((ext_vector_type(4)));
typedef __bf16 bf16_8 __attribute__((ext_vector_type(8)));
typedef float  f32_16 __attribute__((ext_vector_type(16)));

#define NBUOY 16384
#define HID   1024

__device__ __forceinline__ float sigm(float x)  { return 1.f / (1.f + __expf(-x)); }
__device__ __forceinline__ float tanh_f(float x){ return 1.f - 2.f / (1.f + __expf(2.f * x)); }

// Load one 32-K half-tile (j=0,1 sub-steps of 16-K) into named frag set, advance pointers.
#define LOADH(a0, a1, br, bz, bn)                                   \
    a0[0] = *(const bf16_8*)(pa0);      a0[1] = *(const bf16_8*)(pa0 + 16); \
    a1[0] = *(const bf16_8*)(pa1);      a1[1] = *(const bf16_8*)(pa1 + 16); \
    br[0] = *(const bf16_8*)(pbr);      br[1] = *(const bf16_8*)(pbr + 16); \
    bz[0] = *(const bf16_8*)(pbz);      bz[1] = *(const bf16_8*)(pbz + 16); \
    bn[0] = *(const bf16_8*)(pbn);      bn[1] = *(const bf16_8*)(pbn + 16); \
    pa0 += 32; pa1 += 32; pbr += 32; pbz += 32; pbn += 32;

// 12 MFMAs consuming one half-tile set.
#define MFMAH(a0, a1, br, bz, bn)                                                         \
    acc[0][0]  = __builtin_amdgcn_mfma_f32_32x32x16_bf16(a0[0], br[0], acc[0][0], 0,0,0); \
    acc[0][1]  = __builtin_amdgcn_mfma_f32_32x32x16_bf16(a1[0], br[0], acc[0][1], 0,0,0); \
    acc[1][0]  = __builtin_amdgcn_mfma_f32_32x32x16_bf16(a0[0], bz[0], acc[1][0], 0,0,0); \
    acc[1][1]  = __builtin_amdgcn_mfma_f32_32x32x16_bf16(a1[0], bz[0], acc[1][1], 0,0,0); \
    acc[QN][0] = __builtin_amdgcn_mfma_f32_32x32x16_bf16(a0[0], bn[0], acc[QN][0],0,0,0); \
    acc[QN][1] = __builtin_amdgcn_mfma_f32_32x32x16_bf16(a1[0], bn[0], acc[QN][1],0,0,0); \
    acc[0][0]  = __builtin_amdgcn_mfma_f32_32x32x16_bf16(a0[1], br[1], acc[0][0], 0,0,0); \
    acc[0][1]  = __builtin_amdgcn_mfma_f32_32x32x16_bf16(a1[1], br[1], acc[0][1], 0,0,0); \
    acc[1][0]  = __builtin_amdgcn_mfma_f32_32x32x16_bf16(a0[1], bz[1], acc[1][0], 0,0,0); \
    acc[1][1]  = __builtin_amdgcn_mfma_f32_32x32x16_bf16(a1[1], bz[1], acc[1][1], 0,0,0); \
    acc[QN][0] = __builtin_amdgcn_mfma_f32_32x32x16_bf16(a0[1], bn[1], acc[QN][0],0,0,0); \
    acc[QN][1] = __builtin_amdgcn_mfma_f32_32x32x16_bf16(a1[1], bn[1], acc[QN][1],0,0,0);

// One K-phase of the fused GRU GEMM, fully in registers. QN = acc index for this phase's
// "n" contribution (2 = gi_n for IH phase, 3 = gh_n for HH phase).
// Fragment addressing (derived from the verified LDS-read indices of R1):
//   A-frag (32x32x16): lane(l31,hi) reads A[rowBase + l31][k0 + ks*16 + hi*8 .. +8]
//   B-frag:            lane(l31,hi) reads W[gate*1024 + n0 + wn*32 + l31][same k slice]
template<int QN, int K>
__device__ __forceinline__ void phase_direct(
    const __bf16* __restrict__ Ap, long sA, int aRow0,
    const __bf16* __restrict__ Wp, long sW, int n0,
    f32_16 acc[4][2], int tid)
{
    const int lane = tid & 63, wid = tid >> 6;
    const int wm = wid >> 1, wn = wid & 1;
    const int l31 = lane & 31, hi = lane >> 5;

    const __bf16* pa0 = Ap + (long)(aRow0 + wm * 64 +      l31) * sA + hi * 8;
    const __bf16* pa1 = Ap + (long)(aRow0 + wm * 64 + 32 + l31) * sA + hi * 8;
    const __bf16* pbr = Wp + (long)(       n0 + wn * 32 + l31) * sW + hi * 8;
    const __bf16* pbz = Wp + (long)(1024 + n0 + wn * 32 + l31) * sW + hi * 8;
    const __bf16* pbn = Wp + (long)(2048 + n0 + wn * 32 + l31) * sW + hi * 8;

    bf16_8 Xa0[2], Xa1[2], Xbr[2], Xbz[2], Xbn[2];   // pipeline set X
    bf16_8 Ya0[2], Ya1[2], Ybr[2], Ybz[2], Ybn[2];   // pipeline set Y

    constexpr int S = K / 32;          // 32-K stages; S is even for all instantiations
    LOADH(Xa0, Xa1, Xbr, Xbz, Xbn)     // prologue: stage 0

    #pragma unroll 1
    for (int s = 0; s + 2 < S; s += 2) {
        LOADH(Ya0, Ya1, Ybr, Ybz, Ybn)     // stage s+1 in flight
        MFMAH(Xa0, Xa1, Xbr, Xbz, Xbn)     // compute stage s   (waits only X's loads)
        LOADH(Xa0, Xa1, Xbr, Xbz, Xbn)     // stage s+2 in flight
        MFMAH(Ya0, Ya1, Ybr, Ybz, Ybn)     // compute stage s+1 (waits only Y's loads)
    }
    LOADH(Ya0, Ya1, Ybr, Ybz, Ybn)         // stage S-1
    MFMAH(Xa0, Xa1, Xbr, Xbz, Xbn)
    MFMAH(Ya0, Ya1, Ybr, Ybz, Ybn)
}

// h_new = (1-z)*tanh(gi_n + r*gh_n') + z*h_prev
template<int KIH, int KHH, bool USE_E, bool OUT_F32>
__global__ __launch_bounds__(256, 2)
void gru_step(const __bf16* __restrict__ Aih, long sAih,
              const __bf16* __restrict__ Wih,          // bf16, stride 1088
              const __bf16* __restrict__ Ahh,          // bf16, stride 1088
              const __bf16* __restrict__ Whh,          // bf16, stride 1024
              const float*  __restrict__ E,            // 100 x 3072 fp32 (includes b_ih)
              const int*    __restrict__ ids,
              const float*  __restrict__ bih,
              const float*  __restrict__ bhh,
              const __bf16* __restrict__ hprev,        // stride 1088, null for step0
              void* __restrict__ outp, long sOut)
{
    const int tid  = threadIdx.x;
    const int lane = tid & 63, wid = tid >> 6;
    const int wm = wid >> 1, wn = wid & 1;
    const int l31 = lane & 31, hi = lane >> 5;
    const int m0 = blockIdx.y * 128;       // buoy-row base
    const int n0 = blockIdx.x * 64;        // h-col base

    f32_16 acc[4][2];
    #pragma unroll
    for (int q = 0; q < 4; ++q)
        #pragma unroll
        for (int mt = 0; mt < 2; ++mt) acc[q][mt] = (f32_16)(0.0f);

    phase_direct<2, KIH>(Aih, sAih, m0, Wih, 1088, n0, acc, tid);
    if (KHH > 0)
        phase_direct<3, KHH>(Ahh, 1088, m0, Whh, 1024, n0, acc, tid);

    // ---- epilogue: gates ----
    const int col = n0 + wn * 32 + l31;            // 0..1023
    const float bhr = bhh[col], bhz = bhh[1024 + col], bhn = bhh[2048 + col];
    float cir = 0.f, ciz = 0.f, cin = 0.f;
    if (!USE_E) { cir = bih[col]; ciz = bih[1024 + col]; cin = bih[2048 + col]; }

    #pragma unroll
    for (int mt = 0; mt < 2; ++mt) {
        const int rowb = m0 + wm * 64 + mt * 32 + 4 * hi;
        #pragma unroll
        for (int reg = 0; reg < 16; ++reg) {
            const int row = rowb + (reg & 3) + 8 * (reg >> 2);   // C/D layout (m101-verified)
            float er = cir, ez = ciz, en = cin;
            if (USE_E) {
                const float* Ep = E + (long)ids[row] * 3072 + col;
                er = Ep[0]; ez = Ep[1024]; en = Ep[2048];
            }
            const float r  = sigm(acc[0][mt][reg] + er + bhr);
            const float z  = sigm(acc[1][mt][reg] + ez + bhz);
            const float nn = tanh_f(acc[2][mt][reg] + en + r * (acc[3][mt][reg] + bhn));
            float hp = 0.f;
            if (KHH > 0) hp = (float)hprev[(long)row * 1088 + col];
            const float h = (1.f - z) * nn + z * hp;
            if (OUT_F32) ((float*)outp)[(long)row * sOut + col] = h;
            else        ((__bf16*)outp)[(long)row * sOut + col] = (__bf16)h;
        }
    }
}

// E[e][j] = b_ih[j] + sum_k emb[e,k]*W_ih[j][64+k], all fp32. Grid (10 e-tiles, 12 j-tiles).
#define ETILE 10
__global__ void compute_E(const float* __restrict__ emb, const float* __restrict__ Wih,
                          const float* __restrict__ bih, float* __restrict__ E)
{
    __shared__ float semb[ETILE * 1024];   // 40 KB
    const int e0 = blockIdx.x * ETILE;
    const int j  = blockIdx.y * 256 + threadIdx.x;     // 0..3071
    for (int i = threadIdx.x; i < ETILE * 1024; i += 256)
        semb[i] = emb[(long)(e0 + (i >> 10)) * 1024 + (i & 1023)];
    __syncthreads();
    const float* wp = Wih + (long)j * 1088 + 64;
    float a[ETILE];
    const float b = bih[j];
    #pragma unroll
    for (int t = 0; t < ETILE; ++t) a[t] = b;
    for (int k = 0; k < 1024; k += 4) {
        const float4 w = *(const float4*)(wp + k);
        #pragma unroll
        for (int t = 0; t < ETILE; ++t) {
            const float* se = semb + t * 1024 + k;
            a[t] += se[0] * w.x + se[1] * w.y + se[2] * w.z + se[3] * w.w;
        }
    }
    #pragma unroll
    for (int t = 0; t < ETILE; ++t) E[(long)(e0 + t) * 3072 + j] = a[t];
}

// OBS[row][t*64+c] = bf16(obs[row][t][c]) for t=0..2; X0 pad=obs1, X1 pad=obs2.
__global__ void build_obs(const float* __restrict__ obs, __bf16* __restrict__ OBS,
                          __bf16* __restrict__ X0, __bf16* __restrict__ X1)
{
    const int q = blockIdx.x * 256 + threadIdx.x;      // 0 .. 16384*48-1
    const int row = q / 48, w = (q % 48) * 4;          // w in [0,192)
    const float4 v = *(const float4*)(obs + (long)row * 512 + w);
    bf16_4 b; b[0] = (__bf16)v.x; b[1] = (__bf16)v.y; b[2] = (__bf16)v.z; b[3] = (__bf16)v.w;
    *(bf16_4*)(OBS + (long)row * 192 + w) = b;
    if (w >= 64 && w < 128) *(bf16_4*)(X0 + (long)row * 1088 + 1024 + (w - 64))  = b;
    if (w >= 128)           *(bf16_4*)(X1 + (long)row * 1088 + 1024 + (w - 128)) = b;
}

__global__ void cast_f32_bf16(const float* __restrict__ s, __bf16* __restrict__ d, int n4)
{
    const int i = blockIdx.x * 256 + threadIdx.x;
    if (i < n4) {
        const float4 v = ((const float4*)s)[i];
        bf16_4 b; b[0] = (__bf16)v.x; b[1] = (__bf16)v.y; b[2] = (__bf16)v.z; b[3] = (__bf16)v.w;
        ((bf16_4*)d)[i] = b;
    }
}

extern "C" void kernel_launch(void* const* d_in, const int* in_sizes, int n_in,
                              void* d_out, int out_size, void* d_ws, size_t ws_size,
                              hipStream_t stream)
{
    const float* obs = (const float*)d_in[0];
    const int*   ids = (const int*)  d_in[1];
    const float* emb = (const float*)d_in[2];
    const float* Wih = (const float*)d_in[3];
    const float* Whh = (const float*)d_in[4];
    const float* bih = (const float*)d_in[5];
    const float* bhh = (const float*)d_in[6];
    float* out = (float*)d_out;

    const size_t MB = 1 << 20;
    const size_t XB = (size_t)NBUOY * 1088 * 2;        // 35,651,584
    const size_t NEEDED = 21 * MB + 3 * XB;            // ~123 MB
    if (ws_size < NEEDED) return;                      // diagnosable: absmax stays 0.734375

    char* ws = (char*)d_ws;
    float*  E   = (float*) ws;                         // 1.23 MB used (2 MB slot)
    __bf16* Wb  = (__bf16*)(ws + 2 * MB);              // 3072x1088 bf16 (6.7 MB, 7 MB slot)
    __bf16* Ub  = (__bf16*)(ws + 9 * MB);              // 3072x1024 bf16 (6 MB slot)
    __bf16* OBS = (__bf16*)(ws + 15 * MB);             // 16384x192 bf16 (6 MB slot)
    __bf16* X0  = (__bf16*)(ws + 21 * MB);
    __bf16* X1  = (__bf16*)(ws + 21 * MB + XB);
    __bf16* X2  = (__bf16*)(ws + 21 * MB + 2 * XB);

    dim3 blk(256);
    dim3 gridG(HID / 64, NBUOY / 128);                 // x = h-cols (16), y = buoy rows (128)

    cast_f32_bf16<<<(3072 * 1088 / 4 + 255) / 256, blk, 0, stream>>>(Wih, Wb, 3072 * 1088 / 4);
    cast_f32_bf16<<<(3072 * 1024 / 4 + 255) / 256, blk, 0, stream>>>(Whh, Ub, 3072 * 1024 / 4);
    build_obs<<<NBUOY * 48 / 256, blk, 0, stream>>>(obs, OBS, X0, X1);
    compute_E<<<dim3(10, 12), blk, 0, stream>>>(emb, Wih, bih, E);

    // step 0: x=[obs0|id_emb], h=0  -> h0 in X0
    gru_step<64, 0, true, false><<<gridG, blk, 0, stream>>>(
        OBS + 0, 192, Wb, nullptr, Ub, E, ids, bih, bhh, nullptr, X0, 1088);
    // step 1: x=[obs1|id_emb], h=h0 -> h1 in X1
    gru_step<64, 1024, true, false><<<gridG, blk, 0, stream>>>(
        OBS + 64, 192, Wb, X0, Ub, E, ids, bih, bhh, X0, X1, 1088);
    // step 2: x=[obs2|id_emb], h=h1 -> h2 in X2
    gru_step<64, 1024, true, false><<<gridG, blk, 0, stream>>>(
        OBS + 128, 192, Wb, X1, Ub, E, ids, bih, bhh, X1, X2, 1088);
    // step 3: x=[h0|obs1] (=X0, pads hold obs1), h=h2 -> h3 in X1 (X1 pads already obs2)
    gru_step<1088, 1024, false, false><<<gridG, blk, 0, stream>>>(
        X0, 1088, Wb, X2, Ub, nullptr, ids, bih, bhh, X2, X1, 1088);
    // step 4: x=[h3|obs2] (=X1), h=h3 -> fp32 d_out
    gru_step<1088, 1024, false, true><<<gridG, blk, 0, stream>>>(
        X1, 1088, Wb, X1, Ub, nullptr, ids, bih, bhh, X1, out, 1024);
}

// Round 3
// 970.669 us; speedup vs baseline: 2.1641x; 2.1641x over previous
//
#include <hip/hip_runtime.h>
#include <hip/hip_bf16.h>

// ContextualEncoder2: 5 GRU cells, N=16384, H=1024, INPUT=1088. fp32 in/out;
// compute bf16 MFMA + fp32 accumulate (threshold = 2% of max|ref| = 1.47e-2).
// R3: no-LDS, no-barrier GEMM with PACKED operand layouts.
// Packed layout (bf16 elem index), G = row>>5 (32-row groups), K = buffer width:
//   idx(row,k) = G*32K + (k>>4)*512 + ((k>>3)&1)*256 + (row&31)*8 + (k&7)
// => a 32x32x16-MFMA fragment (16B/lane) is ONE contiguous 1KB-aligned wave-load,
//    and consecutive K-steps are consecutive 1KB blocks (linear stream).
// Weights packed once (pack_W); obs packed by build_obs; h written packed by the
// gru_step epilogue itself => every GEMM operand load is coalesced global->VGPR.
// No barriers => compiler emits counted vmcnt => deep cross-tile pipelining.

typedef __bf16 bf16_8 __attribute__((ext_vector_type(8)));
typedef float  f32_16 __attribute__((ext_vector_type(16)));

#define NBUOY 16384
#define HID   1024

__device__ __forceinline__ float sigm(float x)  { return 1.f / (1.f + __expf(-x)); }
__device__ __forceinline__ float tanh_f(float x){ return 1.f - 2.f / (1.f + __expf(2.f * x)); }

// Load one 32-K stage (two 16-K fragments) into a named set; advance stream ptrs.
#define LOADH(a0, a1, br, bz, bn)                                        \
    a0[0] = *(const bf16_8*)(pa0); a0[1] = *(const bf16_8*)(pa0 + 512);  \
    a1[0] = *(const bf16_8*)(pa1); a1[1] = *(const bf16_8*)(pa1 + 512);  \
    br[0] = *(const bf16_8*)(pbr); br[1] = *(const bf16_8*)(pbr + 512);  \
    bz[0] = *(const bf16_8*)(pbz); bz[1] = *(const bf16_8*)(pbz + 512);  \
    bn[0] = *(const bf16_8*)(pbn); bn[1] = *(const bf16_8*)(pbn + 512);  \
    pa0 += 1024; pa1 += 1024; pbr += 1024; pbz += 1024; pbn += 1024;

// 12 MFMAs consuming one 32-K stage.
#define MFMAH(a0, a1, br, bz, bn)                                                         \
    acc[0][0]  = __builtin_amdgcn_mfma_f32_32x32x16_bf16(a0[0], br[0], acc[0][0], 0,0,0); \
    acc[0][1]  = __builtin_amdgcn_mfma_f32_32x32x16_bf16(a1[0], br[0], acc[0][1], 0,0,0); \
    acc[1][0]  = __builtin_amdgcn_mfma_f32_32x32x16_bf16(a0[0], bz[0], acc[1][0], 0,0,0); \
    acc[1][1]  = __builtin_amdgcn_mfma_f32_32x32x16_bf16(a1[0], bz[0], acc[1][1], 0,0,0); \
    acc[QN][0] = __builtin_amdgcn_mfma_f32_32x32x16_bf16(a0[0], bn[0], acc[QN][0],0,0,0); \
    acc[QN][1] = __builtin_amdgcn_mfma_f32_32x32x16_bf16(a1[0], bn[0], acc[QN][1],0,0,0); \
    acc[0][0]  = __builtin_amdgcn_mfma_f32_32x32x16_bf16(a0[1], br[1], acc[0][0], 0,0,0); \
    acc[0][1]  = __builtin_amdgcn_mfma_f32_32x32x16_bf16(a1[1], br[1], acc[0][1], 0,0,0); \
    acc[1][0]  = __builtin_amdgcn_mfma_f32_32x32x16_bf16(a0[1], bz[1], acc[1][0], 0,0,0); \
    acc[1][1]  = __builtin_amdgcn_mfma_f32_32x32x16_bf16(a1[1], bz[1], acc[1][1], 0,0,0); \
    acc[QN][0] = __builtin_amdgcn_mfma_f32_32x32x16_bf16(a0[1], bn[1], acc[QN][0],0,0,0); \
    acc[QN][1] = __builtin_amdgcn_mfma_f32_32x32x16_bf16(a1[1], bn[1], acc[QN][1],0,0,0);

// One K-phase of the fused GRU GEMM from packed buffers.
// QN: acc index for this phase's "n" contribution (2 = gi_n IH, 3 = gh_n HH).
// aGS/wGS: packed group strides (= 32 * K_buffer, in bf16 elems). aG0 = m0>>5.
template<int QN, int K>
__device__ __forceinline__ void phase_direct(
    const __bf16* __restrict__ Ap, long aGS, int aG0,
    const __bf16* __restrict__ Wp, long wGS, int n0,
    f32_16 acc[4][2], int tid)
{
    const int lane = tid & 63, wid = tid >> 6;
    const int wm = wid >> 1, wn = wid & 1;
    const int nG = (n0 >> 5) + wn;                  // weight row-group within gate

    const __bf16* pa0 = Ap + (long)(aG0 + wm * 2    ) * aGS + lane * 8;
    const __bf16* pa1 = Ap + (long)(aG0 + wm * 2 + 1) * aGS + lane * 8;
    const __bf16* pbr = Wp + (long)(      nG) * wGS + lane * 8;   // gate r: rows 0..1023
    const __bf16* pbz = Wp + (long)(32  + nG) * wGS + lane * 8;   // gate z: rows 1024..
    const __bf16* pbn = Wp + (long)(64  + nG) * wGS + lane * 8;   // gate n: rows 2048..

    bf16_8 Xa0[2], Xa1[2], Xbr[2], Xbz[2], Xbn[2];   // pipeline set X
    bf16_8 Ya0[2], Ya1[2], Ybr[2], Ybz[2], Ybn[2];   // pipeline set Y

    constexpr int S = K / 32;          // 32-K stages; even for all instantiations
    LOADH(Xa0, Xa1, Xbr, Xbz, Xbn)     // prologue: stage 0

    #pragma unroll 1
    for (int s = 0; s + 2 < S; s += 2) {
        LOADH(Ya0, Ya1, Ybr, Ybz, Ybn)     // stage s+1 in flight
        MFMAH(Xa0, Xa1, Xbr, Xbz, Xbn)     // compute stage s
        LOADH(Xa0, Xa1, Xbr, Xbz, Xbn)     // stage s+2 in flight
        MFMAH(Ya0, Ya1, Ybr, Ybz, Ybn)     // compute stage s+1
    }
    LOADH(Ya0, Ya1, Ybr, Ybz, Ybn)         // stage S-1
    MFMAH(Xa0, Xa1, Xbr, Xbz, Xbn)
    MFMAH(Ya0, Ya1, Ybr, Ybz, Ybn)
}

// h_new = (1-z)*tanh(gi_n + r*gh_n') + z*h_prev
// All packed buffers that h reads/writes use K=1088 (group stride 34816).
template<int KIH, int KHH, bool USE_E, bool OUT_F32>
__global__ __launch_bounds__(256, 2)
void gru_step(const __bf16* __restrict__ Aih, long aGS,    // packed A for IH phase
              const __bf16* __restrict__ Wih,              // packed, KG=1088
              const __bf16* __restrict__ Ahh,              // packed X, KG=1088
              const __bf16* __restrict__ Whh,              // packed, KG=1024
              const float*  __restrict__ E,                // 100 x 3072 fp32 (has b_ih)
              const int*    __restrict__ ids,
              const float*  __restrict__ bih,
              const float*  __restrict__ bhh,
              const __bf16* __restrict__ hprev,            // packed X, KG=1088
              void* __restrict__ outp, long sOut)
{
    const int tid  = threadIdx.x;
    const int lane = tid & 63, wid = tid >> 6;
    const int wm = wid >> 1, wn = wid & 1;
    const int l31 = lane & 31, hi = lane >> 5;
    const int m0 = blockIdx.y * 128;       // buoy-row base
    const int n0 = blockIdx.x * 64;        // h-col base

    f32_16 acc[4][2];
    #pragma unroll
    for (int q = 0; q < 4; ++q)
        #pragma unroll
        for (int mt = 0; mt < 2; ++mt) acc[q][mt] = (f32_16)(0.0f);

    phase_direct<2, KIH>(Aih, aGS, m0 >> 5, Wih, 34816, n0, acc, tid);
    if (KHH > 0)
        phase_direct<3, KHH>(Ahh, 34816, m0 >> 5, Whh, 32768, n0, acc, tid);

    // ---- epilogue: gates ----
    const int col = n0 + wn * 32 + l31;            // 0..1023
    const float bhr = bhh[col], bhz = bhh[1024 + col], bhn = bhh[2048 + col];
    float cir = 0.f, ciz = 0.f, cin = 0.f;
    if (!USE_E) { cir = bih[col]; ciz = bih[1024 + col]; cin = bih[2048 + col]; }
    // lane-constant part of the packed offset for column `col` (K=1088 buffers)
    const long colPk = (long)(col >> 4) * 512 + ((col >> 3) & 1) * 256 + (col & 7);

    #pragma unroll
    for (int mt = 0; mt < 2; ++mt) {
        const int g = (m0 >> 5) + wm * 2 + mt;     // 32-row group of this m-subtile
        #pragma unroll
        for (int reg = 0; reg < 16; ++reg) {
            const int r = 4 * hi + (reg & 3) + 8 * (reg >> 2);   // row within group
            const int row = g * 32 + r;
            float er = cir, ez = ciz, en = cin;
            if (USE_E) {
                const float* Ep = E + (long)ids[row] * 3072 + col;
                er = Ep[0]; ez = Ep[1024]; en = Ep[2048];
            }
            const float rr = sigm(acc[0][mt][reg] + er + bhr);
            const float z  = sigm(acc[1][mt][reg] + ez + bhz);
            const float nn = tanh_f(acc[2][mt][reg] + en + rr * (acc[3][mt][reg] + bhn));
            float hp = 0.f;
            if (KHH > 0) hp = (float)hprev[(long)g * 34816 + r * 8 + colPk];
            const float h = (1.f - z) * nn + z * hp;
            if (OUT_F32) ((float*)outp)[(long)row * sOut + col] = h;
            else        ((__bf16*)outp)[(long)g * 34816 + r * 8 + colPk] = (__bf16)h;
        }
    }
}

// Pack fp32 weight matrix (3072 x K row-major) -> packed bf16 (group stride 32K).
__global__ void pack_W(const float* __restrict__ W, __bf16* __restrict__ P, int K)
{
    const int q  = blockIdx.x * 256 + threadIdx.x;     // chunk id, 8 bf16 each
    const int kc = q % (K >> 3), row = q / (K >> 3);
    const float4 v0 = *(const float4*)(W + (long)row * K + kc * 8);
    const float4 v1 = *(const float4*)(W + (long)row * K + kc * 8 + 4);
    bf16_8 b;
    b[0] = (__bf16)v0.x; b[1] = (__bf16)v0.y; b[2] = (__bf16)v0.z; b[3] = (__bf16)v0.w;
    b[4] = (__bf16)v1.x; b[5] = (__bf16)v1.y; b[6] = (__bf16)v1.z; b[7] = (__bf16)v1.w;
    const long cidx = (long)(row >> 5) * (K * 4)
                    + (kc >> 1) * 64 + (kc & 1) * 32 + (row & 31);
    ((bf16_8*)P)[cidx] = b;
}

// Pack obs[:,t,:] into OBSp[t] (K=64 layout) and the obs pads of X0 (obs1) / X1 (obs2).
__global__ void build_obs(const float* __restrict__ obs,
                          __bf16* __restrict__ O0, __bf16* __restrict__ O1,
                          __bf16* __restrict__ O2,
                          __bf16* __restrict__ X0, __bf16* __restrict__ X1)
{
    const int q = blockIdx.x * 256 + threadIdx.x;      // 16384 rows x 24 chunks
    const int row = q / 24, c = q % 24;
    const int t = c >> 3, kc = c & 7;
    const float4 v0 = *(const float4*)(obs + (long)row * 512 + t * 64 + kc * 8);
    const float4 v1 = *(const float4*)(obs + (long)row * 512 + t * 64 + kc * 8 + 4);
    bf16_8 b;
    b[0] = (__bf16)v0.x; b[1] = (__bf16)v0.y; b[2] = (__bf16)v0.z; b[3] = (__bf16)v0.w;
    b[4] = (__bf16)v1.x; b[5] = (__bf16)v1.y; b[6] = (__bf16)v1.z; b[7] = (__bf16)v1.w;
    const int g = row >> 5, r = row & 31;
    const long ci = (long)g * 256 + (kc >> 1) * 64 + (kc & 1) * 32 + r;   // K=64
    __bf16* O = (t == 0) ? O0 : (t == 1) ? O1 : O2;
    ((bf16_8*)O)[ci] = b;
    // pads: cols 1024+kc*8 of the K=1088 packed X buffers
    const long cx = (long)g * 4352 + (64 + (kc >> 1)) * 64 + (kc & 1) * 32 + r;
    if (t == 1) ((bf16_8*)X0)[cx] = b;
    if (t == 2) ((bf16_8*)X1)[cx] = b;
}

// E[e][j] = b_ih[j] + sum_k emb[e,k]*W_ih[j][64+k], all fp32 (row-major, unchanged).
#define ETILE 10
__global__ void compute_E(const float* __restrict__ emb, const float* __restrict__ Wih,
                          const float* __restrict__ bih, float* __restrict__ E)
{
    __shared__ float semb[ETILE * 1024];   // 40 KB
    const int e0 = blockIdx.x * ETILE;
    const int j  = blockIdx.y * 256 + threadIdx.x;     // 0..3071
    for (int i = threadIdx.x; i < ETILE * 1024; i += 256)
        semb[i] = emb[(long)(e0 + (i >> 10)) * 1024 + (i & 1023)];
    __syncthreads();
    const float* wp = Wih + (long)j * 1088 + 64;
    float a[ETILE];
    const float b = bih[j];
    #pragma unroll
    for (int t = 0; t < ETILE; ++t) a[t] = b;
    for (int k = 0; k < 1024; k += 4) {
        const float4 w = *(const float4*)(wp + k);
        #pragma unroll
        for (int t = 0; t < ETILE; ++t) {
            const float* se = semb + t * 1024 + k;
            a[t] += se[0] * w.x + se[1] * w.y + se[2] * w.z + se[3] * w.w;
        }
    }
    #pragma unroll
    for (int t = 0; t < ETILE; ++t) E[(long)(e0 + t) * 3072 + j] = a[t];
}

extern "C" void kernel_launch(void* const* d_in, const int* in_sizes, int n_in,
                              void* d_out, int out_size, void* d_ws, size_t ws_size,
                              hipStream_t stream)
{
    const float* obs = (const float*)d_in[0];
    const int*   ids = (const int*)  d_in[1];
    const float* emb = (const float*)d_in[2];
    const float* Wih = (const float*)d_in[3];
    const float* Whh = (const float*)d_in[4];
    const float* bih = (const float*)d_in[5];
    const float* bhh = (const float*)d_in[6];
    float* out = (float*)d_out;

    const size_t MB = 1 << 20;
    const size_t XB = (size_t)NBUOY * 1088 * 2;        // 35,651,584
    const size_t NEEDED = 22 * MB + 3 * XB;            // ~124 MB
    if (ws_size < NEEDED) return;                      // diagnosable: absmax stays 0.734375

    char* ws = (char*)d_ws;
    float*  E    = (float*) ws;                        // 1.23 MB used (2 MB slot)
    __bf16* PWih = (__bf16*)(ws + 2 * MB);             // packed 3072x1088 bf16 (6.7 MB)
    __bf16* PWhh = (__bf16*)(ws + 9 * MB);             // packed 3072x1024 bf16 (6.3 MB)
    __bf16* O0   = (__bf16*)(ws + 16 * MB);            // packed 16384x64 (2 MB each)
    __bf16* O1   = (__bf16*)(ws + 18 * MB);
    __bf16* O2   = (__bf16*)(ws + 20 * MB);
    __bf16* X0   = (__bf16*)(ws + 22 * MB);            // packed 16384x1088
    __bf16* X1   = (__bf16*)(ws + 22 * MB + XB);
    __bf16* X2   = (__bf16*)(ws + 22 * MB + 2 * XB);

    dim3 blk(256);
    dim3 gridG(HID / 64, NBUOY / 128);                 // x = h-cols (16), y = buoy rows (128)

    pack_W<<<3072 * 1088 / 8 / 256, blk, 0, stream>>>(Wih, PWih, 1088);
    pack_W<<<3072 * 1024 / 8 / 256, blk, 0, stream>>>(Whh, PWhh, 1024);
    build_obs<<<NBUOY * 24 / 256, blk, 0, stream>>>(obs, O0, O1, O2, X0, X1);
    compute_E<<<dim3(10, 12), blk, 0, stream>>>(emb, Wih, bih, E);

    // step 0: x=[obs0|id_emb], h=0  -> h0 in X0 (packed)
    gru_step<64, 0, true, false><<<gridG, blk, 0, stream>>>(
        O0, 2048, PWih, nullptr, PWhh, E, ids, bih, bhh, nullptr, X0, 0);
    // step 1: x=[obs1|id_emb], h=h0 -> h1 in X1
    gru_step<64, 1024, true, false><<<gridG, blk, 0, stream>>>(
        O1, 2048, PWih, X0, PWhh, E, ids, bih, bhh, X0, X1, 0);
    // step 2: x=[obs2|id_emb], h=h1 -> h2 in X2
    gru_step<64, 1024, true, false><<<gridG, blk, 0, stream>>>(
        O2, 2048, PWih, X1, PWhh, E, ids, bih, bhh, X1, X2, 0);
    // step 3: x=[h0|obs1] (=X0, pads hold obs1), h=h2 -> h3 in X1 (X1 pads already obs2)
    gru_step<1088, 1024, false, false><<<gridG, blk, 0, stream>>>(
        X0, 34816, PWih, X2, PWhh, nullptr, ids, bih, bhh, X2, X1, 0);
    // step 4: x=[h3|obs2] (=X1), h=h3 -> fp32 d_out (row-major)
    gru_step<1088, 1024, false, true><<<gridG, blk, 0, stream>>>(
        X1, 34816, PWih, X1, PWhh, nullptr, ids, bih, bhh, X1, out, 1024);
}

// Round 7
// 954.583 us; speedup vs baseline: 2.2006x; 1.0169x over previous
//
#include <hip/hip_runtime.h>
#include <hip/hip_bf16.h>

// ContextualEncoder2: 5 GRU cells, N=16384, H=1024, INPUT=1088. fp32 in/out;
// compute bf16 MFMA + fp32 accumulate (threshold = 2% of max|ref| = 1.47e-2).
// R4 (resubmit x3; R4/R5/R6 benches were lost to GPU acquisition timeouts):
// L2-traffic reduction. R1 (LDS) and R3 (packed no-LDS) both hit 258us/37% MfmaUtil:
// both demand ~208 B/cyc/CU of unique operand bytes from L2 vs ~60-78 available.
// Fix: BM=256 (was 128), BN=64, 512 threads / 8 waves (4M x 2N), wave tile 64x32
// (acc stays 8 x f32_16 = 128 VGPR). LDS-staged in the R3 PACKED layout:
//   fragment(32 rows, 16 k) = contiguous 1KB block; global packed idx(row,k) =
//   G*32K + (k>>4)*512 + ((k>>3)&1)*256 + (row&31)*8 + (k&7), G=row>>5.
// global_load_lds copies 1KB blocks linearly; ds_read_b128 at lane*16B is
// conflict-free by construction (no swizzle needed). Double-buffered 112KB LDS,
// stage(t+1) issued before compute(t), one barrier per tile; cross-phase prefetch free.
// 56 blocks/tile = 8 waves x 7 global_load_lds. 112KB LDS => 1 block/CU (8 waves).

typedef __bf16 bf16_8 __attribute__((ext_vector_type(8)));
typedef float  f32_16 __attribute__((ext_vector_type(16)));

#define NBUOY 16384
#define HID   1024
#define BUFSZ 28672   // 56 blocks * 512 elems, per LDS buffer (bf16 elems)

__device__ __forceinline__ void async16(const void* g, void* l) {
    __builtin_amdgcn_global_load_lds(
        (const __attribute__((address_space(1))) unsigned int*)g,
        (__attribute__((address_space(3))) unsigned int*)l, 16, 0, 0);
}
__device__ __forceinline__ float sigm(float x)  { return 1.f / (1.f + __expf(-x)); }
__device__ __forceinline__ float tanh_f(float x){ return 1.f - 2.f / (1.f + __expf(2.f * x)); }

// One K-phase of the fused GRU GEMM. QN = acc index for this phase's "n" quantity
// (2 = gi_n for IH phase, 3 = gh_n for HH phase). aG0 = m0>>5, nG0 = n0>>5.
// buf = current LDS buffer parity (carried across phases for cross-phase prefetch).
template<int QN, int K>
__device__ __forceinline__ void phase_tiled(
    const __bf16* __restrict__ Ap, long aGS, int aG0,
    const __bf16* __restrict__ Wp, long wGS, int nG0,
    __bf16* ls, f32_16 acc[4][2], int tid, int& buf)
{
    const int lane = tid & 63, wid = tid >> 6;
    const int wm = wid >> 1, wn = wid & 1;
    constexpr int NT = K / 64;

    // stage one 64-K tile (56 x 1KB fragment-blocks) into buffer b
    auto stage = [&](int b, int t) {
        __bf16* dst = ls + b * BUFSZ;
        #pragma unroll
        for (int i = 0; i < 7; ++i) {
            const int blk = wid * 7 + i;               // wave-uniform
            const __bf16* src;
            if (blk < 32) {                            // A: 8 groups x 4 kc
                const int g = blk >> 2, kc = blk & 3;
                src = Ap + (long)(aG0 + g) * aGS + (t * 4 + kc) * 512 + lane * 8;
            } else {                                   // B: 3 gates x 2 ng x 4 kc
                const int u = blk - 32;
                const int gate = u >> 3, ng = (u >> 2) & 1, kc = u & 3;
                src = Wp + (long)(gate * 32 + nG0 + ng) * wGS + (t * 4 + kc) * 512 + lane * 8;
            }
            async16(src, dst + blk * 512);
        }
    };

    stage(buf, 0);                      // prologue (overlaps prev phase's last compute)
    #pragma unroll 1
    for (int t = 0; t < NT; ++t) {
        __syncthreads();                // drains vmcnt: tile t staged; prev reads done
        if (t + 1 < NT) stage(buf ^ 1, t + 1);
        const __bf16* base = ls + buf * BUFSZ;
        #pragma unroll
        for (int ks = 0; ks < 4; ++ks) {
            const bf16_8 a0 = *(const bf16_8*)(base + ((wm * 2 + 0) * 4 + ks) * 512 + lane * 8);
            const bf16_8 a1 = *(const bf16_8*)(base + ((wm * 2 + 1) * 4 + ks) * 512 + lane * 8);
            const bf16_8 br = *(const bf16_8*)(base + (32 + ((0 * 2 + wn) * 4 + ks)) * 512 + lane * 8);
            const bf16_8 bz = *(const bf16_8*)(base + (32 + ((1 * 2 + wn) * 4 + ks)) * 512 + lane * 8);
            const bf16_8 bn = *(const bf16_8*)(base + (32 + ((2 * 2 + wn) * 4 + ks)) * 512 + lane * 8);
            acc[0][0]  = __builtin_amdgcn_mfma_f32_32x32x16_bf16(a0, br, acc[0][0], 0, 0, 0);
            acc[0][1]  = __builtin_amdgcn_mfma_f32_32x32x16_bf16(a1, br, acc[0][1], 0, 0, 0);
            acc[1][0]  = __builtin_amdgcn_mfma_f32_32x32x16_bf16(a0, bz, acc[1][0], 0, 0, 0);
            acc[1][1]  = __builtin_amdgcn_mfma_f32_32x32x16_bf16(a1, bz, acc[1][1], 0, 0, 0);
            acc[QN][0] = __builtin_amdgcn_mfma_f32_32x32x16_bf16(a0, bn, acc[QN][0], 0, 0, 0);
            acc[QN][1] = __builtin_amdgcn_mfma_f32_32x32x16_bf16(a1, bn, acc[QN][1], 0, 0, 0);
        }
        buf ^= 1;
    }
}

// h_new = (1-z)*tanh(gi_n + r*gh_n') + z*h_prev
template<int KIH, int KHH, bool USE_E, bool OUT_F32>
__global__ __launch_bounds__(512, 2)
void gru_step(const __bf16* __restrict__ Aih, long aGS,    // packed A for IH phase
              const __bf16* __restrict__ Wih,              // packed, KG=1088
              const __bf16* __restrict__ Ahh,              // packed X, KG=1088
              const __bf16* __restrict__ Whh,              // packed, KG=1024
              const float*  __restrict__ E,                // 100 x 3072 fp32 (has b_ih)
              const int*    __restrict__ ids,
              const float*  __restrict__ bih,
              const float*  __restrict__ bhh,
              const __bf16* __restrict__ hprev,            // packed X, KG=1088
              void* __restrict__ outp, long sOut)
{
    __shared__ __bf16 ls[2 * BUFSZ];       // 112 KB
    const int tid  = threadIdx.x;
    const int lane = tid & 63, wid = tid >> 6;
    const int wm = wid >> 1, wn = wid & 1;
    const int l31 = lane & 31, hi = lane >> 5;
    const int m0 = blockIdx.y * 256;       // buoy-row base
    const int n0 = blockIdx.x * 64;        // h-col base

    f32_16 acc[4][2];
    #pragma unroll
    for (int q = 0; q < 4; ++q)
        #pragma unroll
        for (int mt = 0; mt < 2; ++mt) acc[q][mt] = (f32_16)(0.0f);

    int buf = 0;
    phase_tiled<2, KIH>(Aih, aGS, m0 >> 5, Wih, 34816, n0 >> 5, ls, acc, tid, buf);
    if (KHH > 0)
        phase_tiled<3, KHH>(Ahh, 34816, m0 >> 5, Whh, 32768, n0 >> 5, ls, acc, tid, buf);

    // ---- epilogue: gates ----
    const int col = n0 + wn * 32 + l31;            // 0..1023
    const float bhr = bhh[col], bhz = bhh[1024 + col], bhn = bhh[2048 + col];
    float cir = 0.f, ciz = 0.f, cin = 0.f;
    if (!USE_E) { cir = bih[col]; ciz = bih[1024 + col]; cin = bih[2048 + col]; }
    // lane-constant part of the packed offset for column `col` (K=1088 buffers)
    const long colPk = (long)(col >> 4) * 512 + ((col >> 3) & 1) * 256 + (col & 7);

    #pragma unroll
    for (int mt = 0; mt < 2; ++mt) {
        const int g = (m0 >> 5) + wm * 2 + mt;     // 32-row group of this m-subtile
        #pragma unroll
        for (int reg = 0; reg < 16; ++reg) {
            const int r = 4 * hi + (reg & 3) + 8 * (reg >> 2);   // row within group
            const int row = g * 32 + r;
            float er = cir, ez = ciz, en = cin;
            if (USE_E) {
                const float* Ep = E + (long)ids[row] * 3072 + col;
                er = Ep[0]; ez = Ep[1024]; en = Ep[2048];
            }
            const float rr = sigm(acc[0][mt][reg] + er + bhr);
            const float z  = sigm(acc[1][mt][reg] + ez + bhz);
            const float nn = tanh_f(acc[2][mt][reg] + en + rr * (acc[3][mt][reg] + bhn));
            float hp = 0.f;
            if (KHH > 0) hp = (float)hprev[(long)g * 34816 + r * 8 + colPk];
            const float h = (1.f - z) * nn + z * hp;
            if (OUT_F32) ((float*)outp)[(long)row * sOut + col] = h;
            else        ((__bf16*)outp)[(long)g * 34816 + r * 8 + colPk] = (__bf16)h;
        }
    }
}

// Pack fp32 weight matrix (3072 x K row-major) -> packed bf16 (group stride 32K).
__global__ void pack_W(const float* __restrict__ W, __bf16* __restrict__ P, int K)
{
    const int q  = blockIdx.x * 256 + threadIdx.x;     // chunk id, 8 bf16 each
    const int kc = q % (K >> 3), row = q / (K >> 3);
    const float4 v0 = *(const float4*)(W + (long)row * K + kc * 8);
    const float4 v1 = *(const float4*)(W + (long)row * K + kc * 8 + 4);
    bf16_8 b;
    b[0] = (__bf16)v0.x; b[1] = (__bf16)v0.y; b[2] = (__bf16)v0.z; b[3] = (__bf16)v0.w;
    b[4] = (__bf16)v1.x; b[5] = (__bf16)v1.y; b[6] = (__bf16)v1.z; b[7] = (__bf16)v1.w;
    const long cidx = (long)(row >> 5) * (K * 4)
                    + (kc >> 1) * 64 + (kc & 1) * 32 + (row & 31);
    ((bf16_8*)P)[cidx] = b;
}

// Pack obs[:,t,:] into O0/O1/O2 (K=64 layout) and the obs pads of X0 (obs1) / X1 (obs2).
__global__ void build_obs(const float* __restrict__ obs,
                          __bf16* __restrict__ O0, __bf16* __restrict__ O1,
                          __bf16* __restrict__ O2,
                          __bf16* __restrict__ X0, __bf16* __restrict__ X1)
{
    const int q = blockIdx.x * 256 + threadIdx.x;      // 16384 rows x 24 chunks
    const int row = q / 24, c = q % 24;
    const int t = c >> 3, kc = c & 7;
    const float4 v0 = *(const float4*)(obs + (long)row * 512 + t * 64 + kc * 8);
    const float4 v1 = *(const float4*)(obs + (long)row * 512 + t * 64 + kc * 8 + 4);
    bf16_8 b;
    b[0] = (__bf16)v0.x; b[1] = (__bf16)v0.y; b[2] = (__bf16)v0.z; b[3] = (__bf16)v0.w;
    b[4] = (__bf16)v1.x; b[5] = (__bf16)v1.y; b[6] = (__bf16)v1.z; b[7] = (__bf16)v1.w;
    const int g = row >> 5, r = row & 31;
    const long ci = (long)g * 256 + (kc >> 1) * 64 + (kc & 1) * 32 + r;   // K=64
    __bf16* O = (t == 0) ? O0 : (t == 1) ? O1 : O2;
    ((bf16_8*)O)[ci] = b;
    // pads: cols 1024+kc*8 of the K=1088 packed X buffers
    const long cx = (long)g * 4352 + (64 + (kc >> 1)) * 64 + (kc & 1) * 32 + r;
    if (t == 1) ((bf16_8*)X0)[cx] = b;
    if (t == 2) ((bf16_8*)X1)[cx] = b;
}

// E[e][j] = b_ih[j] + sum_k emb[e,k]*W_ih[j][64+k], all fp32 (row-major, unchanged).
#define ETILE 10
__global__ void compute_E(const float* __restrict__ emb, const float* __restrict__ Wih,
                          const float* __restrict__ bih, float* __restrict__ E)
{
    __shared__ float semb[ETILE * 1024];   // 40 KB
    const int e0 = blockIdx.x * ETILE;
    const int j  = blockIdx.y * 256 + threadIdx.x;     // 0..3071
    for (int i = threadIdx.x; i < ETILE * 1024; i += 256)
        semb[i] = emb[(long)(e0 + (i >> 10)) * 1024 + (i & 1023)];
    __syncthreads();
    const float* wp = Wih + (long)j * 1088 + 64;
    float a[ETILE];
    const float b = bih[j];
    #pragma unroll
    for (int t = 0; t < ETILE; ++t) a[t] = b;
    for (int k = 0; k < 1024; k += 4) {
        const float4 w = *(const float4*)(wp + k);
        #pragma unroll
        for (int t = 0; t < ETILE; ++t) {
            const float* se = semb + t * 1024 + k;
            a[t] += se[0] * w.x + se[1] * w.y + se[2] * w.z + se[3] * w.w;
        }
    }
    #pragma unroll
    for (int t = 0; t < ETILE; ++t) E[(long)(e0 + t) * 3072 + j] = a[t];
}

extern "C" void kernel_launch(void* const* d_in, const int* in_sizes, int n_in,
                              void* d_out, int out_size, void* d_ws, size_t ws_size,
                              hipStream_t stream)
{
    const float* obs = (const float*)d_in[0];
    const int*   ids = (const int*)  d_in[1];
    const float* emb = (const float*)d_in[2];
    const float* Wih = (const float*)d_in[3];
    const float* Whh = (const float*)d_in[4];
    const float* bih = (const float*)d_in[5];
    const float* bhh = (const float*)d_in[6];
    float* out = (float*)d_out;

    const size_t MB = 1 << 20;
    const size_t XB = (size_t)NBUOY * 1088 * 2;        // 35,651,584
    const size_t NEEDED = 22 * MB + 3 * XB;            // ~124 MB
    if (ws_size < NEEDED) return;                      // diagnosable: absmax stays 0.734375

    char* ws = (char*)d_ws;
    float*  E    = (float*) ws;                        // 1.23 MB used (2 MB slot)
    __bf16* PWih = (__bf16*)(ws + 2 * MB);             // packed 3072x1088 bf16 (6.7 MB)
    __bf16* PWhh = (__bf16*)(ws + 9 * MB);             // packed 3072x1024 bf16 (6.3 MB)
    __bf16* O0   = (__bf16*)(ws + 16 * MB);            // packed 16384x64 (2 MB each)
    __bf16* O1   = (__bf16*)(ws + 18 * MB);
    __bf16* O2   = (__bf16*)(ws + 20 * MB);
    __bf16* X0   = (__bf16*)(ws + 22 * MB);            // packed 16384x1088
    __bf16* X1   = (__bf16*)(ws + 22 * MB + XB);
    __bf16* X2   = (__bf16*)(ws + 22 * MB + 2 * XB);

    dim3 blk(256);
    dim3 blkG(512);
    dim3 gridG(HID / 64, NBUOY / 256);                 // x = h-cols (16), y = buoy rows (64)

    pack_W<<<3072 * 1088 / 8 / 256, blk, 0, stream>>>(Wih, PWih, 1088);
    pack_W<<<3072 * 1024 / 8 / 256, blk, 0, stream>>>(Whh, PWhh, 1024);
    build_obs<<<NBUOY * 24 / 256, blk, 0, stream>>>(obs, O0, O1, O2, X0, X1);
    compute_E<<<dim3(10, 12), blk, 0, stream>>>(emb, Wih, bih, E);

    // step 0: x=[obs0|id_emb], h=0  -> h0 in X0 (packed)
    gru_step<64, 0, true, false><<<gridG, blkG, 0, stream>>>(
        O0, 2048, PWih, nullptr, PWhh, E, ids, bih, bhh, nullptr, X0, 0);
    // step 1: x=[obs1|id_emb], h=h0 -> h1 in X1
    gru_step<64, 1024, true, false><<<gridG, blkG, 0, stream>>>(
        O1, 2048, PWih, X0, PWhh, E, ids, bih, bhh, X0, X1, 0);
    // step 2: x=[obs2|id_emb], h=h1 -> h2 in X2
    gru_step<64, 1024, true, false><<<gridG, blkG, 0, stream>>>(
        O2, 2048, PWih, X1, PWhh, E, ids, bih, bhh, X1, X2, 0);
    // step 3: x=[h0|obs1] (=X0, pads hold obs1), h=h2 -> h3 in X1 (X1 pads already obs2)
    gru_step<1088, 1024, false, false><<<gridG, blkG, 0, stream>>>(
        X0, 34816, PWih, X2, PWhh, nullptr, ids, bih, bhh, X2, X1, 0);
    // step 4: x=[h3|obs2] (=X1), h=h3 -> fp32 d_out (row-major)
    gru_step<1088, 1024, false, true><<<gridG, blkG, 0, stream>>>(
        X1, 34816, PWih, X1, PWhh, nullptr, ids, bih, bhh, X1, out, 1024);
}

// Round 8
// 939.311 us; speedup vs baseline: 2.2363x; 1.0163x over previous
//
#include <hip/hip_runtime.h>
#include <hip/hip_bf16.h>

// ContextualEncoder2: 5 GRU cells, N=16384, H=1024, INPUT=1088. fp32 in/out;
// compute bf16 MFMA + fp32 accumulate (threshold = 2% of max|ref| = 1.47e-2).
// R5: XCD-aware blockIdx swizzle on top of R4's BM=256/BN=64 LDS-staged structure.
// Evidence: dur tracks FETCH_SIZE (R3->R4: 0.942 vs 0.926); R1==R3 despite opposite
// structures; per-CU operand rate only ~13 B/cyc (<< L2 ceiling) => bound by operand
// delivery from BEYOND L2 (L3/HBM) due to L2 misses. Default mapping (bid%8->XCD,
// gridDim.x=16) gives each XCD 2 n-slices x 64 y-rows => every A/hprev row fetched
// by 8 XCDs (~553 MB beyond-L2/dispatch). New mapping: each XCD owns 4 n-slices x
// 32 y-rows: W slice 3.2 MB (L2-resident), concurrent set = 4x * 8y shares A 4-ways
// => A-traffic halved (~284 MB). Pure schedule remap; kernel body unchanged from R4.
//   bid 1-D (1024): c=bid&7 (XCD), s=bid>>3; x=(c>>1)*4+(s&3); y=(c&1)*32+(s>>2).

typedef __bf16 bf16_8 __attribute__((ext_vector_type(8)));
typedef float  f32_16 __attribute__((ext_vector_type(16)));

#define NBUOY 16384
#define HID   1024
#define BUFSZ 28672   // 56 blocks * 512 elems, per LDS buffer (bf16 elems)

__device__ __forceinline__ void async16(const void* g, void* l) {
    __builtin_amdgcn_global_load_lds(
        (const __attribute__((address_space(1))) unsigned int*)g,
        (__attribute__((address_space(3))) unsigned int*)l, 16, 0, 0);
}
__device__ __forceinline__ float sigm(float x)  { return 1.f / (1.f + __expf(-x)); }
__device__ __forceinline__ float tanh_f(float x){ return 1.f - 2.f / (1.f + __expf(2.f * x)); }

// One K-phase of the fused GRU GEMM. QN = acc index for this phase's "n" quantity
// (2 = gi_n for IH phase, 3 = gh_n for HH phase). aG0 = m0>>5, nG0 = n0>>5.
// buf = current LDS buffer parity (carried across phases for cross-phase prefetch).
template<int QN, int K>
__device__ __forceinline__ void phase_tiled(
    const __bf16* __restrict__ Ap, long aGS, int aG0,
    const __bf16* __restrict__ Wp, long wGS, int nG0,
    __bf16* ls, f32_16 acc[4][2], int tid, int& buf)
{
    const int lane = tid & 63, wid = tid >> 6;
    const int wm = wid >> 1, wn = wid & 1;
    constexpr int NT = K / 64;

    // stage one 64-K tile (56 x 1KB fragment-blocks) into buffer b
    auto stage = [&](int b, int t) {
        __bf16* dst = ls + b * BUFSZ;
        #pragma unroll
        for (int i = 0; i < 7; ++i) {
            const int blk = wid * 7 + i;               // wave-uniform
            const __bf16* src;
            if (blk < 32) {                            // A: 8 groups x 4 kc
                const int g = blk >> 2, kc = blk & 3;
                src = Ap + (long)(aG0 + g) * aGS + (t * 4 + kc) * 512 + lane * 8;
            } else {                                   // B: 3 gates x 2 ng x 4 kc
                const int u = blk - 32;
                const int gate = u >> 3, ng = (u >> 2) & 1, kc = u & 3;
                src = Wp + (long)(gate * 32 + nG0 + ng) * wGS + (t * 4 + kc) * 512 + lane * 8;
            }
            async16(src, dst + blk * 512);
        }
    };

    stage(buf, 0);                      // prologue (overlaps prev phase's last compute)
    #pragma unroll 1
    for (int t = 0; t < NT; ++t) {
        __syncthreads();                // drains vmcnt: tile t staged; prev reads done
        if (t + 1 < NT) stage(buf ^ 1, t + 1);
        const __bf16* base = ls + buf * BUFSZ;
        #pragma unroll
        for (int ks = 0; ks < 4; ++ks) {
            const bf16_8 a0 = *(const bf16_8*)(base + ((wm * 2 + 0) * 4 + ks) * 512 + lane * 8);
            const bf16_8 a1 = *(const bf16_8*)(base + ((wm * 2 + 1) * 4 + ks) * 512 + lane * 8);
            const bf16_8 br = *(const bf16_8*)(base + (32 + ((0 * 2 + wn) * 4 + ks)) * 512 + lane * 8);
            const bf16_8 bz = *(const bf16_8*)(base + (32 + ((1 * 2 + wn) * 4 + ks)) * 512 + lane * 8);
            const bf16_8 bn = *(const bf16_8*)(base + (32 + ((2 * 2 + wn) * 4 + ks)) * 512 + lane * 8);
            acc[0][0]  = __builtin_amdgcn_mfma_f32_32x32x16_bf16(a0, br, acc[0][0], 0, 0, 0);
            acc[0][1]  = __builtin_amdgcn_mfma_f32_32x32x16_bf16(a1, br, acc[0][1], 0, 0, 0);
            acc[1][0]  = __builtin_amdgcn_mfma_f32_32x32x16_bf16(a0, bz, acc[1][0], 0, 0, 0);
            acc[1][1]  = __builtin_amdgcn_mfma_f32_32x32x16_bf16(a1, bz, acc[1][1], 0, 0, 0);
            acc[QN][0] = __builtin_amdgcn_mfma_f32_32x32x16_bf16(a0, bn, acc[QN][0], 0, 0, 0);
            acc[QN][1] = __builtin_amdgcn_mfma_f32_32x32x16_bf16(a1, bn, acc[QN][1], 0, 0, 0);
        }
        buf ^= 1;
    }
}

// h_new = (1-z)*tanh(gi_n + r*gh_n') + z*h_prev
template<int KIH, int KHH, bool USE_E, bool OUT_F32>
__global__ __launch_bounds__(512, 2)
void gru_step(const __bf16* __restrict__ Aih, long aGS,    // packed A for IH phase
              const __bf16* __restrict__ Wih,              // packed, KG=1088
              const __bf16* __restrict__ Ahh,              // packed X, KG=1088
              const __bf16* __restrict__ Whh,              // packed, KG=1024
              const float*  __restrict__ E,                // 100 x 3072 fp32 (has b_ih)
              const int*    __restrict__ ids,
              const float*  __restrict__ bih,
              const float*  __restrict__ bhh,
              const __bf16* __restrict__ hprev,            // packed X, KG=1088
              void* __restrict__ outp, long sOut)
{
    __shared__ __bf16 ls[2 * BUFSZ];       // 112 KB
    const int tid  = threadIdx.x;
    const int lane = tid & 63, wid = tid >> 6;
    const int wm = wid >> 1, wn = wid & 1;
    const int l31 = lane & 31, hi = lane >> 5;
    // XCD-aware swizzle: bid%8 = XCD (dispatch round-robin). Each XCD owns a
    // 4x-by-32y super-tile; its ~32 concurrent blocks form 4x*8y (A shared 4-ways,
    // W slice 3.2 MB L2-resident). Bijective for 1024 blocks.
    const int bid = blockIdx.x;
    const int c = bid & 7, s = bid >> 3;
    const int xb = (c >> 1) * 4 + (s & 3);     // 0..15  (n-slice)
    const int yb = (c & 1) * 32 + (s >> 2);    // 0..63  (m-row group)
    const int m0 = yb * 256;               // buoy-row base
    const int n0 = xb * 64;                // h-col base

    f32_16 acc[4][2];
    #pragma unroll
    for (int q = 0; q < 4; ++q)
        #pragma unroll
        for (int mt = 0; mt < 2; ++mt) acc[q][mt] = (f32_16)(0.0f);

    int buf = 0;
    phase_tiled<2, KIH>(Aih, aGS, m0 >> 5, Wih, 34816, n0 >> 5, ls, acc, tid, buf);
    if (KHH > 0)
        phase_tiled<3, KHH>(Ahh, 34816, m0 >> 5, Whh, 32768, n0 >> 5, ls, acc, tid, buf);

    // ---- epilogue: gates ----
    const int col = n0 + wn * 32 + l31;            // 0..1023
    const float bhr = bhh[col], bhz = bhh[1024 + col], bhn = bhh[2048 + col];
    float cir = 0.f, ciz = 0.f, cin = 0.f;
    if (!USE_E) { cir = bih[col]; ciz = bih[1024 + col]; cin = bih[2048 + col]; }
    // lane-constant part of the packed offset for column `col` (K=1088 buffers)
    const long colPk = (long)(col >> 4) * 512 + ((col >> 3) & 1) * 256 + (col & 7);

    #pragma unroll
    for (int mt = 0; mt < 2; ++mt) {
        const int g = (m0 >> 5) + wm * 2 + mt;     // 32-row group of this m-subtile
        #pragma unroll
        for (int reg = 0; reg < 16; ++reg) {
            const int r = 4 * hi + (reg & 3) + 8 * (reg >> 2);   // row within group
            const int row = g * 32 + r;
            float er = cir, ez = ciz, en = cin;
            if (USE_E) {
                const float* Ep = E + (long)ids[row] * 3072 + col;
                er = Ep[0]; ez = Ep[1024]; en = Ep[2048];
            }
            const float rr = sigm(acc[0][mt][reg] + er + bhr);
            const float z  = sigm(acc[1][mt][reg] + ez + bhz);
            const float nn = tanh_f(acc[2][mt][reg] + en + rr * (acc[3][mt][reg] + bhn));
            float hp = 0.f;
            if (KHH > 0) hp = (float)hprev[(long)g * 34816 + r * 8 + colPk];
            const float h = (1.f - z) * nn + z * hp;
            if (OUT_F32) ((float*)outp)[(long)row * sOut + col] = h;
            else        ((__bf16*)outp)[(long)g * 34816 + r * 8 + colPk] = (__bf16)h;
        }
    }
}

// Pack fp32 weight matrix (3072 x K row-major) -> packed bf16 (group stride 32K).
__global__ void pack_W(const float* __restrict__ W, __bf16* __restrict__ P, int K)
{
    const int q  = blockIdx.x * 256 + threadIdx.x;     // chunk id, 8 bf16 each
    const int kc = q % (K >> 3), row = q / (K >> 3);
    const float4 v0 = *(const float4*)(W + (long)row * K + kc * 8);
    const float4 v1 = *(const float4*)(W + (long)row * K + kc * 8 + 4);
    bf16_8 b;
    b[0] = (__bf16)v0.x; b[1] = (__bf16)v0.y; b[2] = (__bf16)v0.z; b[3] = (__bf16)v0.w;
    b[4] = (__bf16)v1.x; b[5] = (__bf16)v1.y; b[6] = (__bf16)v1.z; b[7] = (__bf16)v1.w;
    const long cidx = (long)(row >> 5) * (K * 4)
                    + (kc >> 1) * 64 + (kc & 1) * 32 + (row & 31);
    ((bf16_8*)P)[cidx] = b;
}

// Pack obs[:,t,:] into O0/O1/O2 (K=64 layout) and the obs pads of X0 (obs1) / X1 (obs2).
__global__ void build_obs(const float* __restrict__ obs,
                          __bf16* __restrict__ O0, __bf16* __restrict__ O1,
                          __bf16* __restrict__ O2,
                          __bf16* __restrict__ X0, __bf16* __restrict__ X1)
{
    const int q = blockIdx.x * 256 + threadIdx.x;      // 16384 rows x 24 chunks
    const int row = q / 24, c = q % 24;
    const int t = c >> 3, kc = c & 7;
    const float4 v0 = *(const float4*)(obs + (long)row * 512 + t * 64 + kc * 8);
    const float4 v1 = *(const float4*)(obs + (long)row * 512 + t * 64 + kc * 8 + 4);
    bf16_8 b;
    b[0] = (__bf16)v0.x; b[1] = (__bf16)v0.y; b[2] = (__bf16)v0.z; b[3] = (__bf16)v0.w;
    b[4] = (__bf16)v1.x; b[5] = (__bf16)v1.y; b[6] = (__bf16)v1.z; b[7] = (__bf16)v1.w;
    const int g = row >> 5, r = row & 31;
    const long ci = (long)g * 256 + (kc >> 1) * 64 + (kc & 1) * 32 + r;   // K=64
    __bf16* O = (t == 0) ? O0 : (t == 1) ? O1 : O2;
    ((bf16_8*)O)[ci] = b;
    // pads: cols 1024+kc*8 of the K=1088 packed X buffers
    const long cx = (long)g * 4352 + (64 + (kc >> 1)) * 64 + (kc & 1) * 32 + r;
    if (t == 1) ((bf16_8*)X0)[cx] = b;
    if (t == 2) ((bf16_8*)X1)[cx] = b;
}

// E[e][j] = b_ih[j] + sum_k emb[e,k]*W_ih[j][64+k], all fp32 (row-major, unchanged).
#define ETILE 10
__global__ void compute_E(const float* __restrict__ emb, const float* __restrict__ Wih,
                          const float* __restrict__ bih, float* __restrict__ E)
{
    __shared__ float semb[ETILE * 1024];   // 40 KB
    const int e0 = blockIdx.x * ETILE;
    const int j  = blockIdx.y * 256 + threadIdx.x;     // 0..3071
    for (int i = threadIdx.x; i < ETILE * 1024; i += 256)
        semb[i] = emb[(long)(e0 + (i >> 10)) * 1024 + (i & 1023)];
    __syncthreads();
    const float* wp = Wih + (long)j * 1088 + 64;
    float a[ETILE];
    const float b = bih[j];
    #pragma unroll
    for (int t = 0; t < ETILE; ++t) a[t] = b;
    for (int k = 0; k < 1024; k += 4) {
        const float4 w = *(const float4*)(wp + k);
        #pragma unroll
        for (int t = 0; t < ETILE; ++t) {
            const float* se = semb + t * 1024 + k;
            a[t] += se[0] * w.x + se[1] * w.y + se[2] * w.z + se[3] * w.w;
        }
    }
    #pragma unroll
    for (int t = 0; t < ETILE; ++t) E[(long)(e0 + t) * 3072 + j] = a[t];
}

extern "C" void kernel_launch(void* const* d_in, const int* in_sizes, int n_in,
                              void* d_out, int out_size, void* d_ws, size_t ws_size,
                              hipStream_t stream)
{
    const float* obs = (const float*)d_in[0];
    const int*   ids = (const int*)  d_in[1];
    const float* emb = (const float*)d_in[2];
    const float* Wih = (const float*)d_in[3];
    const float* Whh = (const float*)d_in[4];
    const float* bih = (const float*)d_in[5];
    const float* bhh = (const float*)d_in[6];
    float* out = (float*)d_out;

    const size_t MB = 1 << 20;
    const size_t XB = (size_t)NBUOY * 1088 * 2;        // 35,651,584
    const size_t NEEDED = 22 * MB + 3 * XB;            // ~124 MB
    if (ws_size < NEEDED) return;                      // diagnosable: absmax stays 0.734375

    char* ws = (char*)d_ws;
    float*  E    = (float*) ws;                        // 1.23 MB used (2 MB slot)
    __bf16* PWih = (__bf16*)(ws + 2 * MB);             // packed 3072x1088 bf16 (6.7 MB)
    __bf16* PWhh = (__bf16*)(ws + 9 * MB);             // packed 3072x1024 bf16 (6.3 MB)
    __bf16* O0   = (__bf16*)(ws + 16 * MB);            // packed 16384x64 (2 MB each)
    __bf16* O1   = (__bf16*)(ws + 18 * MB);
    __bf16* O2   = (__bf16*)(ws + 20 * MB);
    __bf16* X0   = (__bf16*)(ws + 22 * MB);            // packed 16384x1088
    __bf16* X1   = (__bf16*)(ws + 22 * MB + XB);
    __bf16* X2   = (__bf16*)(ws + 22 * MB + 2 * XB);

    dim3 blk(256);
    dim3 blkG(512);
    dim3 gridG(16 * 64);                               // 1-D, XCD-swizzled in-kernel

    pack_W<<<3072 * 1088 / 8 / 256, blk, 0, stream>>>(Wih, PWih, 1088);
    pack_W<<<3072 * 1024 / 8 / 256, blk, 0, stream>>>(Whh, PWhh, 1024);
    build_obs<<<NBUOY * 24 / 256, blk, 0, stream>>>(obs, O0, O1, O2, X0, X1);
    compute_E<<<dim3(10, 12), blk, 0, stream>>>(emb, Wih, bih, E);

    // step 0: x=[obs0|id_emb], h=0  -> h0 in X0 (packed)
    gru_step<64, 0, true, false><<<gridG, blkG, 0, stream>>>(
        O0, 2048, PWih, nullptr, PWhh, E, ids, bih, bhh, nullptr, X0, 0);
    // step 1: x=[obs1|id_emb], h=h0 -> h1 in X1
    gru_step<64, 1024, true, false><<<gridG, blkG, 0, stream>>>(
        O1, 2048, PWih, X0, PWhh, E, ids, bih, bhh, X0, X1, 0);
    // step 2: x=[obs2|id_emb], h=h1 -> h2 in X2
    gru_step<64, 1024, true, false><<<gridG, blkG, 0, stream>>>(
        O2, 2048, PWih, X1, PWhh, E, ids, bih, bhh, X1, X2, 0);
    // step 3: x=[h0|obs1] (=X0, pads hold obs1), h=h2 -> h3 in X1 (X1 pads already obs2)
    gru_step<1088, 1024, false, false><<<gridG, blkG, 0, stream>>>(
        X0, 34816, PWih, X2, PWhh, nullptr, ids, bih, bhh, X2, X1, 0);
    // step 4: x=[h3|obs2] (=X1), h=h3 -> fp32 d_out (row-major)
    gru_step<1088, 1024, false, true><<<gridG, blkG, 0, stream>>>(
        X1, 34816, PWih, X1, PWhh, nullptr, ids, bih, bhh, X1, out, 1024);
}